// Round 9
// baseline (323.527 us; speedup 1.0000x reference)
//
#include <hip/hip_runtime.h>
#include <hip/hip_bf16.h>

using short8  = __attribute__((ext_vector_type(8))) short;
using ushort8 = __attribute__((ext_vector_type(8))) unsigned short;
using floatx4 = __attribute__((ext_vector_type(4))) float;

#define EPSV 1e-4f

__device__ __forceinline__ unsigned short bfbits(float f) {
  __hip_bfloat16 h = __float2bfloat16(f);
  return *reinterpret_cast<unsigned short*>(&h);
}

// ---------------- prep: weight cvt f32 -> bf16 (contiguous dst) ----------------
__global__ void prep_kernel(const float4* __restrict__ Wf, const float4* __restrict__ W1,
                            const float4* __restrict__ W2, const float4* __restrict__ W3,
                            const float4* __restrict__ W4, ushort4* __restrict__ wdst) {
  int t = blockIdx.x * 256 + threadIdx.x;   // 159744 exact (624 blocks)
  const float4* src; int off;
  if (t < 98304)       { src = Wf; off = 0; }
  else if (t < 131072) { src = W1; off = 98304; }
  else if (t < 147456) { src = W2; off = 131072; }
  else if (t < 155648) { src = W3; off = 147456; }
  else                 { src = W4; off = 155648; }
  float4 v = src[t - off];
  ushort4 o;
  o.x = bfbits(v.x); o.y = bfbits(v.y); o.z = bfbits(v.z); o.w = bfbits(v.w);
  wdst[t] = o;
}

// ---------------- fused L0..L4 + distances + act ----------------
template <int N, int K, int ACT, int OUTF32>
__device__ __forceinline__ void layer_lds(const unsigned short* __restrict__ A, int astride,
                                          const __hip_bfloat16* __restrict__ W,
                                          const float* __restrict__ bias,
                                          void* __restrict__ Cout, int cstride,
                                          int w, int r, int q) {
  constexpr int NA = N / 64;
  const int n0 = w * (N / 4);
  floatx4 acc[NA] = {};
#pragma unroll
  for (int k0 = 0; k0 < K; k0 += 32) {
    short8 a = *reinterpret_cast<const short8*>(A + r * astride + k0 + q * 8);
#pragma unroll
    for (int ni = 0; ni < NA; ++ni) {
      short8 b = *reinterpret_cast<const short8*>(W + (size_t)(n0 + ni * 16 + r) * K + k0 + q * 8);
      acc[ni] = __builtin_amdgcn_mfma_f32_16x16x32_bf16(a, b, acc[ni], 0, 0, 0);
    }
  }
#pragma unroll
  for (int ni = 0; ni < NA; ++ni) {
    float bv = bias[n0 + ni * 16 + r];
#pragma unroll
    for (int rr = 0; rr < 4; ++rr) {
      float v = acc[ni][rr] + bv;
      v = (ACT == 0) ? fmaxf(v, 0.0f) : 1.0f / (1.0f + __expf(-v));
      if (OUTF32)
        reinterpret_cast<float*>(Cout)[(q * 4 + rr) * cstride + n0 + ni * 16 + r] = v;
      else
        reinterpret_cast<unsigned short*>(Cout)[(q * 4 + rr) * cstride + n0 + ni * 16 + r] = bfbits(v);
    }
  }
}

__global__ __launch_bounds__(256) void mlp_dist_kernel(
    const float* __restrict__ x,
    const __hip_bfloat16* __restrict__ WfB, const float* __restrict__ bias0,
    const __hip_bfloat16* __restrict__ W1B, const float* __restrict__ b1,
    const __hip_bfloat16* __restrict__ W2B, const float* __restrict__ b2,
    const __hip_bfloat16* __restrict__ W3B, const float* __restrict__ b3,
    const __hip_bfloat16* __restrict__ W4B, const float* __restrict__ b4,
    const float* __restrict__ proto,
    float* __restrict__ dist, float* __restrict__ act,
    float* __restrict__ out_logits) {
  __shared__ unsigned short bufF[16 * 520];   // f  (bf16), stride 520
  __shared__ unsigned short bufA[16 * 264];   // h1 / h3 (bf16)
  __shared__ unsigned short bufB[16 * 264];   // h2 (bf16)
  __shared__ float          h4f[16 * 132];    // h4 (f32, for distances)
  __shared__ float          ps[60 * 132];     // prototypes f32, stride 132
  const int t = threadIdx.x;
  const int w = t >> 6;
  const int lane = t & 63;
  const int r = lane & 15;
  const int q = lane >> 4;
  const int pos0 = blockIdx.x * 16;    // 196 blocks

  // zero logits for the atomic accumulation in the final launch
  if (blockIdx.x == 0 && t < 48) out_logits[t] = 0.0f;

  // stage prototypes (f32, padded stride 132)
  {
    const float4* p4 = reinterpret_cast<const float4*>(proto);
    for (int i = t; i < 1920; i += 256) {
      int p = i >> 5, kc = i & 31;
      *reinterpret_cast<float4*>(&ps[p * 132 + kc * 4]) = p4[i];
    }
  }

  // L0: f = relu(patch(x) * Wf^T + bf); A-frag loaded DIRECTLY from x.
  {
    int pos = pos0 + r;
    int b = pos / 196;
    int ij = pos - b * 196;
    int i = ij / 14;
    int j = ij - i * 14;
    const float* xb = x + (size_t)b * 150528 + (i * 16) * 224 + j * 16;
    floatx4 acc[8] = {};
#pragma unroll 4
    for (int k0 = 0; k0 < 768; k0 += 32) {
      int k = k0 + q * 8;
      int c = k >> 8;
      int kh = (k >> 4) & 15;
      int kw0 = k & 15;              // 0 or 8
      const float* ap = xb + c * 50176 + kh * 224 + kw0;
      float4 lo = *reinterpret_cast<const float4*>(ap);
      float4 hi = *reinterpret_cast<const float4*>(ap + 4);
      short8 a;
      a[0] = bfbits(lo.x); a[1] = bfbits(lo.y); a[2] = bfbits(lo.z); a[3] = bfbits(lo.w);
      a[4] = bfbits(hi.x); a[5] = bfbits(hi.y); a[6] = bfbits(hi.z); a[7] = bfbits(hi.w);
#pragma unroll
      for (int ni = 0; ni < 8; ++ni) {
        short8 bfr = *reinterpret_cast<const short8*>(
            WfB + (size_t)(w * 128 + ni * 16 + r) * 768 + k0 + q * 8);
        acc[ni] = __builtin_amdgcn_mfma_f32_16x16x32_bf16(a, bfr, acc[ni], 0, 0, 0);
      }
    }
#pragma unroll
    for (int ni = 0; ni < 8; ++ni) {
      float bv = bias0[w * 128 + ni * 16 + r];
#pragma unroll
      for (int rr = 0; rr < 4; ++rr)
        bufF[(q * 4 + rr) * 520 + w * 128 + ni * 16 + r] = bfbits(fmaxf(acc[ni][rr] + bv, 0.0f));
    }
  }
  __syncthreads();
  layer_lds<256, 512, 0, 0>(bufF, 520, W1B, b1, bufA, 264, w, r, q);
  __syncthreads();
  layer_lds<256, 256, 0, 0>(bufA, 264, W2B, b2, bufB, 264, w, r, q);
  __syncthreads();
  layer_lds<128, 256, 0, 0>(bufB, 264, W3B, b3, bufA, 264, w, r, q);
  __syncthreads();
  layer_lds<128, 128, 1, 1>(bufA, 264, W4B, b4, h4f, 132, w, r, q);
  __syncthreads();

  // distances + act from LDS h4 (f32) and ps — float4 vectorized
  for (int qq = t; qq < 960; qq += 256) {
    int p = qq >> 4;          // 0..59
    int pos = qq & 15;
    const float4* hv4 = reinterpret_cast<const float4*>(&h4f[pos * 132]);
    const float4* pv4 = reinterpret_cast<const float4*>(&ps[p * 132]);
    float s = 0.0f;
#pragma unroll 8
    for (int k = 0; k < 32; ++k) {
      float4 hv = hv4[k];
      float4 pv = pv4[k];
      float d0 = hv.x - pv.x, d1 = hv.y - pv.y, d2 = hv.z - pv.z, d3 = hv.w - pv.w;
      s = fmaf(d0, d0, s); s = fmaf(d1, d1, s); s = fmaf(d2, d2, s); s = fmaf(d3, d3, s);
    }
    float d = sqrtf(s);
    float a = __logf((d + 1.0f) / (d + EPSV));
    int gpos = pos0 + pos;
    int bimg = gpos / 196;
    int hw = gpos - bimg * 196;
    size_t idx = ((size_t)bimg * 60 + p) * 196 + hw;
    dist[idx] = d;
    act[idx] = a;
  }
}

// ---------------- final: upsample (blocks 0..23549, 32 B/thread, nontemporal)
//                  + topk/logits tail (240 blocks) ----------------
__global__ void final_kernel(const float* __restrict__ act,
                             float* __restrict__ up,
                             const float* __restrict__ dist,
                             const float* __restrict__ lastW,
                             float* __restrict__ out_logits,
                             float* __restrict__ out_mind) {
  if (blockIdx.x < 23550) {
    // thread t covers 8 consecutive floats (2 x 16B) = one half of a 16-run
    int t = blockIdx.x * 256 + threadIdx.x;   // 6,028,800 exact
    int col8 = t % 28;                        // 28 chunks of 8 per 224-row
    int rem = t / 28;
    int y = rem % 224;
    int bp = rem / 224;
    float v = act[(size_t)bp * 196 + (y >> 4) * 14 + (col8 >> 1)];
    floatx4 val = {v, v, v, v};
    floatx4* dst = reinterpret_cast<floatx4*>(up) + (size_t)t * 2;
    __builtin_nontemporal_store(val, dst);
    __builtin_nontemporal_store(val, dst + 1);
  } else {
    // top-5 smallest distances per (b,p): one wave per unit.
    // act = log((d+1)/(d+eps)) is strictly decreasing in d.
    const int wid = threadIdx.x >> 6;
    const int lane = threadIdx.x & 63;
    const int u = (blockIdx.x - 23550) * 4 + wid;   // 0..959 exact
    const float* rowp = dist + (size_t)u * 196;

    float v[4];
#pragma unroll
    for (int i = 0; i < 4; ++i) {
      int idx = lane + 64 * i;
      v[i] = (idx < 196) ? rowp[idx] : 1e30f;
    }

    float sd = 0.0f, sa = 0.0f;
#pragma unroll
    for (int round = 0; round < 5; ++round) {
      float lmin = fminf(fminf(v[0], v[1]), fminf(v[2], v[3]));
      float m = lmin;
#pragma unroll
      for (int off = 32; off >= 1; off >>= 1)
        m = fminf(m, __shfl_xor(m, off));
      unsigned long long msk = __ballot(lmin == m);
      int leader = __ffsll((long long)msk) - 1;
      if (lane == leader) {
        if (v[0] == m)      v[0] = 1e30f;
        else if (v[1] == m) v[1] = 1e30f;
        else if (v[2] == m) v[2] = 1e30f;
        else                v[3] = 1e30f;
      }
      sd += m;
      sa += __logf((m + 1.0f) / (m + EPSV));
    }
    int b = u / 60, p = u - b * 60;
    float pa = sa * 0.2f;
    if (lane == 0) out_mind[u] = sd * 0.2f;
    if (lane < 3) atomicAdd(&out_logits[b * 3 + lane], pa * lastW[lane * 60 + p]);
  }
}

extern "C" void kernel_launch(void* const* d_in, const int* in_sizes, int n_in,
                              void* d_out, int out_size, void* d_ws, size_t ws_size,
                              hipStream_t stream) {
  const float* x     = (const float*)d_in[0];
  const float* Wf    = (const float*)d_in[2];   // [512,768]
  const float* bf    = (const float*)d_in[3];
  const float* W1    = (const float*)d_in[4];   // [256,512]
  const float* b1    = (const float*)d_in[5];
  const float* W2    = (const float*)d_in[6];   // [256,256]
  const float* b2    = (const float*)d_in[7];
  const float* W3    = (const float*)d_in[8];   // [128,256]
  const float* b3    = (const float*)d_in[9];
  const float* W4    = (const float*)d_in[10];  // [128,128]
  const float* b4    = (const float*)d_in[11];
  const float* proto = (const float*)d_in[12];  // [60,128]
  const float* lastW = (const float*)d_in[13];  // [3,60]

  char* ws = (char*)d_ws;
  __hip_bfloat16* WfB = (__hip_bfloat16*)(ws + 0);         // 393216 elems
  __hip_bfloat16* W1B = (__hip_bfloat16*)(ws + 786432);    // 131072
  __hip_bfloat16* W2B = (__hip_bfloat16*)(ws + 1048576);   // 65536
  __hip_bfloat16* W3B = (__hip_bfloat16*)(ws + 1179648);   // 32768
  __hip_bfloat16* W4B = (__hip_bfloat16*)(ws + 1245184);   // 16384
  float* dist = (float*)(ws + 1310720);                    // [960,196] f32
  float* act  = (float*)(ws + 2063360);                    // [960,196] f32

  float* out        = (float*)d_out;
  float* out_logits = out;          // 48
  float* out_mind   = out + 48;     // 960
  float* out_up     = out + 1008;   // 48,230,400

  prep_kernel<<<624, 256, 0, stream>>>((const float4*)Wf, (const float4*)W1,
                                       (const float4*)W2, (const float4*)W3,
                                       (const float4*)W4, (ushort4*)WfB);
  mlp_dist_kernel<<<196, 256, 0, stream>>>(x, WfB, bf, W1B, b1, W2B, b2,
                                           W3B, b3, W4B, b4, proto, dist, act,
                                           out_logits);
  final_kernel<<<23790, 256, 0, stream>>>(act, out_up, dist, lastW,
                                          out_logits, out_mind);
}

// Round 10
// 270.054 us; speedup vs baseline: 1.1980x; 1.1980x over previous
//
#include <hip/hip_runtime.h>
#include <hip/hip_bf16.h>

using short8  = __attribute__((ext_vector_type(8))) short;
using ushort8 = __attribute__((ext_vector_type(8))) unsigned short;
using floatx4 = __attribute__((ext_vector_type(4))) float;

#define EPSV 1e-4f

__device__ __forceinline__ unsigned short bfbits(float f) {
  __hip_bfloat16 h = __float2bfloat16(f);
  return *reinterpret_cast<unsigned short*>(&h);
}

// ---------------- prep: weight cvt f32 -> bf16 (contiguous dst) ----------------
__global__ void prep_kernel(const float4* __restrict__ Wf, const float4* __restrict__ W1,
                            const float4* __restrict__ W2, const float4* __restrict__ W3,
                            const float4* __restrict__ W4, ushort4* __restrict__ wdst) {
  int t = blockIdx.x * 256 + threadIdx.x;   // 159744 exact (624 blocks)
  const float4* src; int off;
  if (t < 98304)       { src = Wf; off = 0; }
  else if (t < 131072) { src = W1; off = 98304; }
  else if (t < 147456) { src = W2; off = 131072; }
  else if (t < 155648) { src = W3; off = 147456; }
  else                 { src = W4; off = 155648; }
  float4 v = src[t - off];
  ushort4 o;
  o.x = bfbits(v.x); o.y = bfbits(v.y); o.z = bfbits(v.z); o.w = bfbits(v.w);
  wdst[t] = o;
}

// ---------------- fused L0..L4 + distances + act ----------------
template <int N, int K, int ACT, int OUTF32>
__device__ __forceinline__ void layer_lds(const unsigned short* __restrict__ A, int astride,
                                          const __hip_bfloat16* __restrict__ W,
                                          const float* __restrict__ bias,
                                          void* __restrict__ Cout, int cstride,
                                          int w, int r, int q) {
  constexpr int NA = N / 64;
  const int n0 = w * (N / 4);
  floatx4 acc[NA] = {};
#pragma unroll
  for (int k0 = 0; k0 < K; k0 += 32) {
    short8 a = *reinterpret_cast<const short8*>(A + r * astride + k0 + q * 8);
#pragma unroll
    for (int ni = 0; ni < NA; ++ni) {
      short8 b = *reinterpret_cast<const short8*>(W + (size_t)(n0 + ni * 16 + r) * K + k0 + q * 8);
      acc[ni] = __builtin_amdgcn_mfma_f32_16x16x32_bf16(a, b, acc[ni], 0, 0, 0);
    }
  }
#pragma unroll
  for (int ni = 0; ni < NA; ++ni) {
    float bv = bias[n0 + ni * 16 + r];
#pragma unroll
    for (int rr = 0; rr < 4; ++rr) {
      float v = acc[ni][rr] + bv;
      v = (ACT == 0) ? fmaxf(v, 0.0f) : 1.0f / (1.0f + __expf(-v));
      if (OUTF32)
        reinterpret_cast<float*>(Cout)[(q * 4 + rr) * cstride + n0 + ni * 16 + r] = v;
      else
        reinterpret_cast<unsigned short*>(Cout)[(q * 4 + rr) * cstride + n0 + ni * 16 + r] = bfbits(v);
    }
  }
}

__global__ __launch_bounds__(256) void mlp_dist_kernel(
    const float* __restrict__ x,
    const __hip_bfloat16* __restrict__ WfB, const float* __restrict__ bias0,
    const __hip_bfloat16* __restrict__ W1B, const float* __restrict__ b1,
    const __hip_bfloat16* __restrict__ W2B, const float* __restrict__ b2,
    const __hip_bfloat16* __restrict__ W3B, const float* __restrict__ b3,
    const __hip_bfloat16* __restrict__ W4B, const float* __restrict__ b4,
    const float* __restrict__ proto,
    float* __restrict__ dist, float* __restrict__ act,
    float* __restrict__ out_logits) {
  __shared__ unsigned short bufF[16 * 520];   // f  (bf16), stride 520
  __shared__ unsigned short bufA[16 * 264];   // h1 / h3 (bf16)
  __shared__ unsigned short bufB[16 * 264];   // h2 (bf16)
  __shared__ float          h4f[16 * 132];    // h4 (f32, for distances)
  __shared__ float          ps[60 * 132];     // prototypes f32, stride 132
  const int t = threadIdx.x;
  const int w = t >> 6;
  const int lane = t & 63;
  const int r = lane & 15;
  const int q = lane >> 4;
  const int pos0 = blockIdx.x * 16;    // 196 blocks

  // zero logits for the atomic accumulation in the final launch
  if (blockIdx.x == 0 && t < 48) out_logits[t] = 0.0f;

  // stage prototypes (f32, padded stride 132)
  {
    const float4* p4 = reinterpret_cast<const float4*>(proto);
    for (int i = t; i < 1920; i += 256) {
      int p = i >> 5, kc = i & 31;
      *reinterpret_cast<float4*>(&ps[p * 132 + kc * 4]) = p4[i];
    }
  }

  // L0: f = relu(patch(x) * Wf^T + bf); A-frag loaded DIRECTLY from x.
  {
    int pos = pos0 + r;
    int b = pos / 196;
    int ij = pos - b * 196;
    int i = ij / 14;
    int j = ij - i * 14;
    const float* xb = x + (size_t)b * 150528 + (i * 16) * 224 + j * 16;
    floatx4 acc[8] = {};
#pragma unroll 4
    for (int k0 = 0; k0 < 768; k0 += 32) {
      int k = k0 + q * 8;
      int c = k >> 8;
      int kh = (k >> 4) & 15;
      int kw0 = k & 15;              // 0 or 8
      const float* ap = xb + c * 50176 + kh * 224 + kw0;
      float4 lo = *reinterpret_cast<const float4*>(ap);
      float4 hi = *reinterpret_cast<const float4*>(ap + 4);
      short8 a;
      a[0] = bfbits(lo.x); a[1] = bfbits(lo.y); a[2] = bfbits(lo.z); a[3] = bfbits(lo.w);
      a[4] = bfbits(hi.x); a[5] = bfbits(hi.y); a[6] = bfbits(hi.z); a[7] = bfbits(hi.w);
#pragma unroll
      for (int ni = 0; ni < 8; ++ni) {
        short8 bfr = *reinterpret_cast<const short8*>(
            WfB + (size_t)(w * 128 + ni * 16 + r) * 768 + k0 + q * 8);
        acc[ni] = __builtin_amdgcn_mfma_f32_16x16x32_bf16(a, bfr, acc[ni], 0, 0, 0);
      }
    }
#pragma unroll
    for (int ni = 0; ni < 8; ++ni) {
      float bv = bias0[w * 128 + ni * 16 + r];
#pragma unroll
      for (int rr = 0; rr < 4; ++rr)
        bufF[(q * 4 + rr) * 520 + w * 128 + ni * 16 + r] = bfbits(fmaxf(acc[ni][rr] + bv, 0.0f));
    }
  }
  __syncthreads();
  layer_lds<256, 512, 0, 0>(bufF, 520, W1B, b1, bufA, 264, w, r, q);
  __syncthreads();
  layer_lds<256, 256, 0, 0>(bufA, 264, W2B, b2, bufB, 264, w, r, q);
  __syncthreads();
  layer_lds<128, 256, 0, 0>(bufB, 264, W3B, b3, bufA, 264, w, r, q);
  __syncthreads();
  layer_lds<128, 128, 1, 1>(bufA, 264, W4B, b4, h4f, 132, w, r, q);
  __syncthreads();

  // distances + act from LDS h4 (f32) and ps — float4 vectorized
  for (int qq = t; qq < 960; qq += 256) {
    int p = qq >> 4;          // 0..59
    int pos = qq & 15;
    const float4* hv4 = reinterpret_cast<const float4*>(&h4f[pos * 132]);
    const float4* pv4 = reinterpret_cast<const float4*>(&ps[p * 132]);
    float s = 0.0f;
#pragma unroll 8
    for (int k = 0; k < 32; ++k) {
      float4 hv = hv4[k];
      float4 pv = pv4[k];
      float d0 = hv.x - pv.x, d1 = hv.y - pv.y, d2 = hv.z - pv.z, d3 = hv.w - pv.w;
      s = fmaf(d0, d0, s); s = fmaf(d1, d1, s); s = fmaf(d2, d2, s); s = fmaf(d3, d3, s);
    }
    float d = sqrtf(s);
    float a = __logf((d + 1.0f) / (d + EPSV));
    int gpos = pos0 + pos;
    int bimg = gpos / 196;
    int hw = gpos - bimg * 196;
    size_t idx = ((size_t)bimg * 60 + p) * 196 + hw;
    dist[idx] = d;
    act[idx] = a;
  }
}

// ---------------- final: upsample (blocks 0..47099, 16 B/thread contiguous)
//                  + topk/logits tail (240 blocks) ----------------
// NOTE (r9 post-mortem): 32 B/thread + nontemporal stores regressed +55 µs —
// per-instruction lane stride 32 B leaves every 64 B line half-written, and
// nt eviction forces partial-line RMW at HBM. Keep one float4/thread: each
// wave store = 1 KiB fully contiguous, every line completed in-instruction.
__global__ void final_kernel(const float* __restrict__ act,
                             float* __restrict__ up,
                             const float* __restrict__ dist,
                             const float* __restrict__ lastW,
                             float* __restrict__ out_logits,
                             float* __restrict__ out_mind) {
  if (blockIdx.x < 47100) {
    int t = blockIdx.x * 256 + threadIdx.x;   // 12,057,600 exact
    int col4 = t % 56;
    int rem = t / 56;
    int y = rem % 224;
    int bp = rem / 224;
    float v = act[(size_t)bp * 196 + (y >> 4) * 14 + (col4 >> 2)];
    float4 val;
    val.x = v; val.y = v; val.z = v; val.w = v;
    reinterpret_cast<float4*>(up)[t] = val;
  } else {
    // top-5 smallest distances per (b,p): one wave per unit.
    // act = log((d+1)/(d+eps)) is strictly decreasing in d.
    const int wid = threadIdx.x >> 6;
    const int lane = threadIdx.x & 63;
    const int u = (blockIdx.x - 47100) * 4 + wid;   // 0..959 exact
    const float* rowp = dist + (size_t)u * 196;

    float v[4];
#pragma unroll
    for (int i = 0; i < 4; ++i) {
      int idx = lane + 64 * i;
      v[i] = (idx < 196) ? rowp[idx] : 1e30f;
    }

    float sd = 0.0f, sa = 0.0f;
#pragma unroll
    for (int round = 0; round < 5; ++round) {
      float lmin = fminf(fminf(v[0], v[1]), fminf(v[2], v[3]));
      float m = lmin;
#pragma unroll
      for (int off = 32; off >= 1; off >>= 1)
        m = fminf(m, __shfl_xor(m, off));
      unsigned long long msk = __ballot(lmin == m);
      int leader = __ffsll((long long)msk) - 1;
      if (lane == leader) {
        if (v[0] == m)      v[0] = 1e30f;
        else if (v[1] == m) v[1] = 1e30f;
        else if (v[2] == m) v[2] = 1e30f;
        else                v[3] = 1e30f;
      }
      sd += m;
      sa += __logf((m + 1.0f) / (m + EPSV));
    }
    int b = u / 60, p = u - b * 60;
    float pa = sa * 0.2f;
    if (lane == 0) out_mind[u] = sd * 0.2f;
    if (lane < 3) atomicAdd(&out_logits[b * 3 + lane], pa * lastW[lane * 60 + p]);
  }
}

extern "C" void kernel_launch(void* const* d_in, const int* in_sizes, int n_in,
                              void* d_out, int out_size, void* d_ws, size_t ws_size,
                              hipStream_t stream) {
  const float* x     = (const float*)d_in[0];
  const float* Wf    = (const float*)d_in[2];   // [512,768]
  const float* bf    = (const float*)d_in[3];
  const float* W1    = (const float*)d_in[4];   // [256,512]
  const float* b1    = (const float*)d_in[5];
  const float* W2    = (const float*)d_in[6];   // [256,256]
  const float* b2    = (const float*)d_in[7];
  const float* W3    = (const float*)d_in[8];   // [128,256]
  const float* b3    = (const float*)d_in[9];
  const float* W4    = (const float*)d_in[10];  // [128,128]
  const float* b4    = (const float*)d_in[11];
  const float* proto = (const float*)d_in[12];  // [60,128]
  const float* lastW = (const float*)d_in[13];  // [3,60]

  char* ws = (char*)d_ws;
  __hip_bfloat16* WfB = (__hip_bfloat16*)(ws + 0);         // 393216 elems
  __hip_bfloat16* W1B = (__hip_bfloat16*)(ws + 786432);    // 131072
  __hip_bfloat16* W2B = (__hip_bfloat16*)(ws + 1048576);   // 65536
  __hip_bfloat16* W3B = (__hip_bfloat16*)(ws + 1179648);   // 32768
  __hip_bfloat16* W4B = (__hip_bfloat16*)(ws + 1245184);   // 16384
  float* dist = (float*)(ws + 1310720);                    // [960,196] f32
  float* act  = (float*)(ws + 2063360);                    // [960,196] f32

  float* out        = (float*)d_out;
  float* out_logits = out;          // 48
  float* out_mind   = out + 48;     // 960
  float* out_up     = out + 1008;   // 48,230,400

  prep_kernel<<<624, 256, 0, stream>>>((const float4*)Wf, (const float4*)W1,
                                       (const float4*)W2, (const float4*)W3,
                                       (const float4*)W4, (ushort4*)WfB);
  mlp_dist_kernel<<<196, 256, 0, stream>>>(x, WfB, bf, W1B, b1, W2B, b2,
                                           W3B, b3, W4B, b4, proto, dist, act,
                                           out_logits);
  final_kernel<<<47340, 256, 0, stream>>>(act, out_up, dist, lastW,
                                          out_logits, out_mind);
}